// Round 2
// baseline (493.366 us; speedup 1.0000x reference)
//
#include <hip/hip_runtime.h>
#include <hip/hip_bf16.h>
#include <math.h>

#define D_MODEL 1024
#define H_NUM 16
#define HD 64
#define FF_DIM 2048
#define SEQ 2048
#define BATCH 4
#define M_TOK 8192  // BATCH*SEQ

typedef __attribute__((ext_vector_type(8))) short bf16x8;
typedef __attribute__((ext_vector_type(4))) float f32x4;

__device__ __forceinline__ short f2bf(float f) {
  __hip_bfloat16 h = __float2bfloat16(f);
  return *reinterpret_cast<short*>(&h);
}

__device__ __forceinline__ void gload16(const void* g, void* l) {
  __builtin_amdgcn_global_load_lds((const __attribute__((address_space(1))) void*)g,
                                   (__attribute__((address_space(3))) void*)l, 16, 0, 0);
}

// ---------------- weight transpose + cast: src fp32 [K][N] -> dst bf16 [N][K]
__global__ __launch_bounds__(256) void transpose_cast(const float* __restrict__ src,
                                                      short* __restrict__ dst,
                                                      int K, int N) {
  __shared__ float tile[64][65];
  const int n0 = blockIdx.x * 64, k0 = blockIdx.y * 64;
  const int tr = threadIdx.x >> 4;         // 0..15
  const int tc = (threadIdx.x & 15) * 4;   // 0..60
#pragma unroll
  for (int i = 0; i < 4; ++i) {
    int kr = tr + i * 16;
    float4 v = *(const float4*)(src + (size_t)(k0 + kr) * N + n0 + tc);
    tile[kr][tc] = v.x; tile[kr][tc + 1] = v.y; tile[kr][tc + 2] = v.z; tile[kr][tc + 3] = v.w;
  }
  __syncthreads();
#pragma unroll
  for (int i = 0; i < 4; ++i) {
    int r = tr + i * 16;
    short4 o;
    o.x = f2bf(tile[tc][r]);
    o.y = f2bf(tile[tc + 1][r]);
    o.z = f2bf(tile[tc + 2][r]);
    o.w = f2bf(tile[tc + 3][r]);
    *(short4*)(dst + (size_t)(n0 + r) * K + k0 + tc) = o;
  }
}

// ---------------- LayerNorm fp32 [rows][1024] -> bf16, one block per row
__global__ __launch_bounds__(256) void ln_bf16(const float* __restrict__ x,
                                               const float* __restrict__ g,
                                               const float* __restrict__ b,
                                               short* __restrict__ out) {
  const int row = blockIdx.x;
  const int t = threadIdx.x;
  const float* xr = x + (size_t)row * D_MODEL;
  float4 v = *(const float4*)(xr + t * 4);
  float s = v.x + v.y + v.z + v.w;
  float s2 = v.x * v.x + v.y * v.y + v.z * v.z + v.w * v.w;
#pragma unroll
  for (int m = 1; m < 64; m <<= 1) { s += __shfl_xor(s, m); s2 += __shfl_xor(s2, m); }
  __shared__ float ps[8];
  const int wid = t >> 6, lane = t & 63;
  if (lane == 0) { ps[wid] = s; ps[wid + 4] = s2; }
  __syncthreads();
  s = ps[0] + ps[1] + ps[2] + ps[3];
  s2 = ps[4] + ps[5] + ps[6] + ps[7];
  float mu = s * (1.f / D_MODEL);
  float rstd = rsqrtf(s2 * (1.f / D_MODEL) - mu * mu + 1e-5f);
  float4 gv = *(const float4*)(g + t * 4);
  float4 bv = *(const float4*)(b + t * 4);
  short4 o;
  o.x = f2bf((v.x - mu) * rstd * gv.x + bv.x);
  o.y = f2bf((v.y - mu) * rstd * gv.y + bv.y);
  o.z = f2bf((v.z - mu) * rstd * gv.z + bv.z);
  o.w = f2bf((v.w - mu) * rstd * gv.w + bv.w);
  *(short4*)(out + (size_t)row * D_MODEL + t * 4) = o;
}

// ---------------- 128x128 bf16 MFMA GEMM, BK=64, swizzled LDS, epilogue by MODE
// A [M][K] bf16 row-major; Bt [N][K] bf16 (B transposed). C = A*B.
// MODE 0: QKV scatter. q,k -> [BH][S][HD] (q scaled by 1/8*log2e); v -> [BH][HD][S]
// MODE 1: C + bias0 + resid -> outf (fp32)
// MODE 2: gelu(C + bias0) -> outb0 (bf16)
// MODE 3: C + bias0 + resid -> outf (fp32)   (resid may alias outf)
template <int MODE>
__global__ __launch_bounds__(256) void gemm128(const short* __restrict__ A,
                                               const short* __restrict__ Bt,
                                               const float* __restrict__ bias0,
                                               const float* __restrict__ bias1,
                                               const float* __restrict__ bias2,
                                               const float* resid, float* outf,
                                               short* outb0, short* outb1, short* outb2,
                                               int M, int N, int K) {
  __shared__ short As[128 * 64];
  __shared__ short Bs[128 * 64];
  const int tid = threadIdx.x;
  const int lane = tid & 63;
  const int wid = tid >> 6;
  const int wr = wid >> 1, wc = wid & 1;
  const int row0 = blockIdx.y * 128, col0 = blockIdx.x * 128;

  f32x4 acc[4][4];
#pragma unroll
  for (int i = 0; i < 4; ++i)
#pragma unroll
    for (int j = 0; j < 4; ++j) acc[i][j] = (f32x4){0.f, 0.f, 0.f, 0.f};

  const int str = tid >> 3;                  // staging row within 32-row group
  const int sch = (tid & 7) ^ (str & 7);     // pre-swizzled source chunk

  for (int k0 = 0; k0 < K; k0 += 64) {
#pragma unroll
    for (int c = 0; c < 4; ++c) {
      int r = c * 32 + str;
      gload16(A + (size_t)(row0 + r) * K + k0 + sch * 8, (char*)As + c * 4096 + tid * 16);
      gload16(Bt + (size_t)(col0 + r) * K + k0 + sch * 8, (char*)Bs + c * 4096 + tid * 16);
    }
    __syncthreads();
#pragma unroll
    for (int kk = 0; kk < 2; ++kk) {
      bf16x8 af[4], bfr[4];
#pragma unroll
      for (int mf = 0; mf < 4; ++mf) {
        int rr = wr * 64 + mf * 16 + (lane & 15);
        int ch = (kk * 4 + (lane >> 4)) ^ (rr & 7);
        af[mf] = *(const bf16x8*)((const char*)As + rr * 128 + ch * 16);
      }
#pragma unroll
      for (int nf = 0; nf < 4; ++nf) {
        int rr = wc * 64 + nf * 16 + (lane & 15);
        int ch = (kk * 4 + (lane >> 4)) ^ (rr & 7);
        bfr[nf] = *(const bf16x8*)((const char*)Bs + rr * 128 + ch * 16);
      }
#pragma unroll
      for (int mf = 0; mf < 4; ++mf)
#pragma unroll
        for (int nf = 0; nf < 4; ++nf)
          acc[mf][nf] = __builtin_amdgcn_mfma_f32_16x16x32_bf16(af[mf], bfr[nf], acc[mf][nf], 0, 0, 0);
    }
    __syncthreads();
  }

#pragma unroll
  for (int mf = 0; mf < 4; ++mf) {
#pragma unroll
    for (int nf = 0; nf < 4; ++nf) {
      const int rowb = row0 + wr * 64 + mf * 16 + ((lane >> 4) << 2);
      const int col = col0 + wc * 64 + nf * 16 + (lane & 15);
      if (MODE == 0) {
        const int which = col >> 10, nn = col & 1023;
        const int hh = nn >> 6, dd = nn & 63;
        const float bias = (which == 0 ? bias0[nn] : which == 1 ? bias1[nn] : bias2[nn]);
        if (which == 2) {
          // V transposed: [BH][HD][SEQ]; 4 consecutive seq -> short4
          const int bb = rowb >> 11, s = rowb & 2047;
          short4 o;
#pragma unroll
          for (int r = 0; r < 4; ++r) {
            float val = acc[mf][nf][r] + bias;
            ((short*)&o)[r] = f2bf(val);
          }
          *(short4*)(outb2 + ((size_t)((bb << 4) + hh) * HD + dd) * SEQ + s) = o;
        } else {
#pragma unroll
          for (int r = 0; r < 4; ++r) {
            const int row = rowb + r;
            float val = acc[mf][nf][r] + bias;
            if (which == 0) val *= 0.18033688011112042f;  // 1/8 * log2(e)
            const int bb = row >> 11, s = row & 2047;
            const size_t dst = (((size_t)((bb << 4) + hh) << 11) + s) * HD + dd;
            (which == 0 ? outb0 : outb1)[dst] = f2bf(val);
          }
        }
      } else {
#pragma unroll
        for (int r = 0; r < 4; ++r) {
          const int row = rowb + r;
          float val = acc[mf][nf][r];
          if (MODE == 2) {
            val += bias0[col];
            float gl = 0.5f * val * (1.f + erff(val * 0.70710678118f));
            outb0[(size_t)row * N + col] = f2bf(gl);
          } else {  // MODE 1 and 3
            val += bias0[col] + resid[(size_t)row * N + col];
            outf[(size_t)row * N + col] = val;
          }
        }
      }
    }
  }
}

// ---------------- flash attention: grid (qtiles=32, bh=64), 256 threads
// q,k bf16 [BH][SEQ][HD] (q pre-scaled by 1/8*log2e). vT bf16 [BH][HD][SEQ].
// ctx bf16 [B][SEQ][D] token-major. KVBLK=128, double-buffered staging.
__global__ __launch_bounds__(256) void attn128(const short* __restrict__ q,
                                               const short* __restrict__ k,
                                               const short* __restrict__ vT,
                                               short* __restrict__ ctx) {
  __shared__ short Ks[2][8192];   // [128 key][64 d], swizzled 128B rows
  __shared__ short VTs[2][8192];  // [64 d][128 key], swizzled 256B rows
  __shared__ short Ps[8192];      // [64 q][128 key], swizzled 256B rows
  const int tid = threadIdx.x;
  const int lane = tid & 63;
  const int wid = tid >> 6;
  const int qt = blockIdx.x, bh = blockIdx.y;
  const size_t base = (size_t)bh * SEQ * HD;  // same for vT ([BH][HD][SEQ])

  // Q fragments: this wave's 16 q-rows
  bf16x8 aq[2];
#pragma unroll
  for (int kk = 0; kk < 2; ++kk)
    aq[kk] = *(const bf16x8*)(q + base + (size_t)(qt * 64 + wid * 16 + (lane & 15)) * HD +
                              kk * 32 + (lane >> 4) * 8);

  float mreg[4], lreg[4];
  f32x4 oc[4];
#pragma unroll
  for (int r = 0; r < 4; ++r) { mreg[r] = -1e30f; lreg[r] = 0.f; }
#pragma unroll
  for (int c = 0; c < 4; ++c) oc[c] = (f32x4){0.f, 0.f, 0.f, 0.f};

  const int kch = (tid & 7) ^ ((tid >> 3) & 7);    // K staging swizzled chunk
  const int vch = (tid & 15) ^ ((tid >> 4) & 7);   // VT staging swizzled chunk

  // stage K[kt] tile (128x64) and VT[kt] tile (64x128) into buffer bi
#define STAGE(bi, kt)                                                                  \
  {                                                                                    \
    const short* kb_ = k + base + (size_t)(kt) * 128 * HD;                             \
    const short* vb_ = vT + base + (size_t)(kt) * 128;                                 \
    _Pragma("unroll") for (int p = 0; p < 4; ++p)                                      \
        gload16(kb_ + (size_t)(p * 32 + (tid >> 3)) * HD + kch * 8,                    \
                (char*)Ks[bi] + p * 4096 + tid * 16);                                  \
    _Pragma("unroll") for (int p = 0; p < 4; ++p)                                      \
        gload16(vb_ + (size_t)(p * 16 + (tid >> 4)) * SEQ + vch * 8,                   \
                (char*)VTs[bi] + p * 4096 + tid * 16);                                 \
  }

  STAGE(0, 0);
  __syncthreads();
  int cur = 0;

  for (int kt = 0; kt < 16; ++kt) {
    if (kt + 1 < 16) STAGE(cur ^ 1, kt + 1);

    // S = Q K^T : 8 key-frags x 2 k-slices
    f32x4 sf[8];
#pragma unroll
    for (int c = 0; c < 8; ++c) {
      sf[c] = (f32x4){0.f, 0.f, 0.f, 0.f};
#pragma unroll
      for (int kk = 0; kk < 2; ++kk) {
        int rr = c * 16 + (lane & 15);
        int ch = (kk * 4 + (lane >> 4)) ^ (rr & 7);
        bf16x8 bk = *(const bf16x8*)((const char*)Ks[cur] + rr * 128 + ch * 16);
        sf[c] = __builtin_amdgcn_mfma_f32_16x16x32_bf16(aq[kk], bk, sf[c], 0, 0, 0);
      }
    }

    // online softmax (base-2 domain; q pre-scaled by log2e)
    float mx[4];
#pragma unroll
    for (int r = 0; r < 4; ++r) {
      mx[r] = sf[0][r];
#pragma unroll
      for (int c = 1; c < 8; ++c) mx[r] = fmaxf(mx[r], sf[c][r]);
    }
#pragma unroll
    for (int m = 1; m < 16; m <<= 1)
#pragma unroll
      for (int r = 0; r < 4; ++r) mx[r] = fmaxf(mx[r], __shfl_xor(mx[r], m));
    float alpha[4], rs[4];
#pragma unroll
    for (int r = 0; r < 4; ++r) {
      float mn = fmaxf(mreg[r], mx[r]);
      alpha[r] = exp2f(mreg[r] - mn);
      mreg[r] = mn;
      rs[r] = 0.f;
    }
#pragma unroll
    for (int c = 0; c < 8; ++c)
#pragma unroll
      for (int r = 0; r < 4; ++r) {
        float p = exp2f(sf[c][r] - mreg[r]);
        sf[c][r] = p;
        rs[r] += p;
      }
#pragma unroll
    for (int m = 1; m < 16; m <<= 1)
#pragma unroll
      for (int r = 0; r < 4; ++r) rs[r] += __shfl_xor(rs[r], m);
#pragma unroll
    for (int r = 0; r < 4; ++r) lreg[r] = lreg[r] * alpha[r] + rs[r];
#pragma unroll
    for (int c = 0; c < 4; ++c)
#pragma unroll
      for (int r = 0; r < 4; ++r) oc[c][r] *= alpha[r];

    // write P bf16 to this wave's own rows (wave-local, no barrier)
#pragma unroll
    for (int c = 0; c < 8; ++c)
#pragma unroll
      for (int r = 0; r < 4; ++r) {
        int prow = wid * 16 + ((lane >> 4) << 2) + r;
        int off = (prow * 256 + (c * 16 + (lane & 15)) * 2) ^ ((prow & 7) << 4);
        *(short*)((char*)Ps + off) = f2bf(sf[c][r]);
      }

    // ctx += P V : A = P rows, B = VT (col=d, k=key)
    bf16x8 ap[4];
#pragma unroll
    for (int ks = 0; ks < 4; ++ks) {
      int prow = wid * 16 + (lane & 15);
      int off = (prow * 256 + ks * 64 + (lane >> 4) * 16) ^ ((prow & 7) << 4);
      ap[ks] = *(const bf16x8*)((const char*)Ps + off);
    }
#pragma unroll
    for (int c = 0; c < 4; ++c)
#pragma unroll
      for (int ks = 0; ks < 4; ++ks) {
        int rr = c * 16 + (lane & 15);
        int ch = (ks * 4 + (lane >> 4)) ^ (rr & 7);
        bf16x8 bv = *(const bf16x8*)((const char*)VTs[cur] + rr * 256 + ch * 16);
        oc[c] = __builtin_amdgcn_mfma_f32_16x16x32_bf16(ap[ks], bv, oc[c], 0, 0, 0);
      }
    __syncthreads();
    cur ^= 1;
  }
#undef STAGE

  // normalize and write ctx in [B][S][D] token-major layout
  const int b = bh >> 4, hh = bh & 15;
#pragma unroll
  for (int c = 0; c < 4; ++c)
#pragma unroll
    for (int r = 0; r < 4; ++r) {
      int s = qt * 64 + wid * 16 + ((lane >> 4) << 2) + r;
      size_t off = ((size_t)(b * SEQ + s)) * D_MODEL + hh * HD + c * 16 + (lane & 15);
      ctx[off] = f2bf(oc[c][r] / lreg[r]);
    }
}

// ---------------- launcher
extern "C" void kernel_launch(void* const* d_in, const int* in_sizes, int n_in,
                              void* d_out, int out_size, void* d_ws, size_t ws_size,
                              hipStream_t stream) {
  const float* x  = (const float*)d_in[0];
  const float* Wq = (const float*)d_in[1];
  const float* bq = (const float*)d_in[2];
  const float* Wk = (const float*)d_in[3];
  const float* bk = (const float*)d_in[4];
  const float* Wv = (const float*)d_in[5];
  const float* bv = (const float*)d_in[6];
  const float* Wo = (const float*)d_in[7];
  const float* bo = (const float*)d_in[8];
  const float* g1 = (const float*)d_in[9];
  const float* b1 = (const float*)d_in[10];
  const float* g2 = (const float*)d_in[11];
  const float* b2 = (const float*)d_in[12];
  const float* W1 = (const float*)d_in[13];
  const float* bf1 = (const float*)d_in[14];
  const float* W2 = (const float*)d_in[15];
  const float* bf2 = (const float*)d_in[16];

  char* w = (char*)d_ws;
  short* WqkvT = (short*)w; w += (size_t)3072 * 1024 * 2;      // 6 MB
  short* WoT   = (short*)w; w += (size_t)1024 * 1024 * 2;      // 2 MB
  short* W1T   = (short*)w; w += (size_t)2048 * 1024 * 2;      // 4 MB
  short* W2T   = (short*)w; w += (size_t)1024 * 2048 * 2;      // 4 MB
  short* xn    = (short*)w; w += (size_t)M_TOK * 1024 * 2;     // 16 MB
  short* qb    = (short*)w; w += (size_t)M_TOK * 1024 * 2;
  short* kb    = (short*)w; w += (size_t)M_TOK * 1024 * 2;
  short* vTb   = (short*)w; w += (size_t)M_TOK * 1024 * 2;     // [BH][HD][SEQ]
  short* ctxb  = (short*)w; w += (size_t)M_TOK * 1024 * 2;
  short* xn2   = (short*)w; w += (size_t)M_TOK * 1024 * 2;
  short* hb    = (short*)w; w += (size_t)M_TOK * 2048 * 2;     // 32 MB

  dim3 blk(256);

  // weights -> bf16 transposed
  transpose_cast<<<dim3(16, 16), blk, 0, stream>>>(Wq, WqkvT, 1024, 1024);
  transpose_cast<<<dim3(16, 16), blk, 0, stream>>>(Wk, WqkvT + 1024 * 1024, 1024, 1024);
  transpose_cast<<<dim3(16, 16), blk, 0, stream>>>(Wv, WqkvT + 2 * 1024 * 1024, 1024, 1024);
  transpose_cast<<<dim3(16, 16), blk, 0, stream>>>(Wo, WoT, 1024, 1024);
  transpose_cast<<<dim3(32, 16), blk, 0, stream>>>(W1, W1T, 1024, 2048);
  transpose_cast<<<dim3(16, 32), blk, 0, stream>>>(W2, W2T, 2048, 1024);

  // LN1
  ln_bf16<<<M_TOK, blk, 0, stream>>>(x, g1, b1, xn);

  // QKV projection (fused 3072-wide GEMM, scatter q/k head-major, v transposed)
  gemm128<0><<<dim3(24, 64), blk, 0, stream>>>(xn, WqkvT, bq, bk, bv,
                                               nullptr, nullptr, qb, kb, vTb,
                                               M_TOK, 3072, 1024);

  // attention
  attn128<<<dim3(32, 64), blk, 0, stream>>>(qb, kb, vTb, ctxb);

  // out proj + residual -> d_out (fp32 x2)
  gemm128<1><<<dim3(8, 64), blk, 0, stream>>>(ctxb, WoT, bo, nullptr, nullptr,
                                              x, (float*)d_out, nullptr, nullptr, nullptr,
                                              M_TOK, 1024, 1024);

  // LN2 on x2
  ln_bf16<<<M_TOK, blk, 0, stream>>>((const float*)d_out, g2, b2, xn2);

  // FFN1 + GELU
  gemm128<2><<<dim3(16, 64), blk, 0, stream>>>(xn2, W1T, bf1, nullptr, nullptr,
                                               nullptr, nullptr, hb, nullptr, nullptr,
                                               M_TOK, 2048, 1024);

  // FFN2 + residual (in-place on d_out)
  gemm128<3><<<dim3(8, 64), blk, 0, stream>>>(hb, W2T, bf2, nullptr, nullptr,
                                              (const float*)d_out, (float*)d_out,
                                              nullptr, nullptr, nullptr,
                                              M_TOK, 1024, 2048);
}

// Round 3
// 381.479 us; speedup vs baseline: 1.2933x; 1.2933x over previous
//
#include <hip/hip_runtime.h>
#include <hip/hip_bf16.h>
#include <math.h>

#define D_MODEL 1024
#define H_NUM 16
#define HD 64
#define FF_DIM 2048
#define SEQ 2048
#define BATCH 4
#define M_TOK 8192  // BATCH*SEQ

typedef __attribute__((ext_vector_type(8))) short bf16x8;
typedef __attribute__((ext_vector_type(4))) float f32x4;
typedef __attribute__((ext_vector_type(16))) float f32x16;
typedef __attribute__((ext_vector_type(4))) unsigned int uint4v;
typedef __attribute__((ext_vector_type(2))) int int2v;

__device__ __forceinline__ short f2bf(float f) {
  __hip_bfloat16 h = __float2bfloat16(f);
  return *reinterpret_cast<short*>(&h);
}

__device__ __forceinline__ void gload16(const void* g, void* l) {
  __builtin_amdgcn_global_load_lds((const __attribute__((address_space(1))) void*)g,
                                   (__attribute__((address_space(3))) void*)l, 16, 0, 0);
}

__device__ __forceinline__ unsigned cvt_pk_bf16(float lo, float hi) {
  unsigned r;
  asm("v_cvt_pk_bf16_f32 %0, %1, %2" : "=v"(r) : "v"(lo), "v"(hi));
  return r;
}

// ---------------- weight transpose + cast: src fp32 [K][N] -> dst bf16 [N][K]
__global__ __launch_bounds__(256) void transpose_cast(const float* __restrict__ src,
                                                      short* __restrict__ dst,
                                                      int K, int N) {
  __shared__ float tile[64][65];
  const int n0 = blockIdx.x * 64, k0 = blockIdx.y * 64;
  const int tr = threadIdx.x >> 4;         // 0..15
  const int tc = (threadIdx.x & 15) * 4;   // 0..60
#pragma unroll
  for (int i = 0; i < 4; ++i) {
    int kr = tr + i * 16;
    float4 v = *(const float4*)(src + (size_t)(k0 + kr) * N + n0 + tc);
    tile[kr][tc] = v.x; tile[kr][tc + 1] = v.y; tile[kr][tc + 2] = v.z; tile[kr][tc + 3] = v.w;
  }
  __syncthreads();
#pragma unroll
  for (int i = 0; i < 4; ++i) {
    int r = tr + i * 16;
    short4 o;
    o.x = f2bf(tile[tc][r]);
    o.y = f2bf(tile[tc + 1][r]);
    o.z = f2bf(tile[tc + 2][r]);
    o.w = f2bf(tile[tc + 3][r]);
    *(short4*)(dst + (size_t)(n0 + r) * K + k0 + tc) = o;
  }
}

// ---------------- LayerNorm fp32 [rows][1024] -> bf16, one block per row
__global__ __launch_bounds__(256) void ln_bf16(const float* __restrict__ x,
                                               const float* __restrict__ g,
                                               const float* __restrict__ b,
                                               short* __restrict__ out) {
  const int row = blockIdx.x;
  const int t = threadIdx.x;
  const float* xr = x + (size_t)row * D_MODEL;
  float4 v = *(const float4*)(xr + t * 4);
  float s = v.x + v.y + v.z + v.w;
  float s2 = v.x * v.x + v.y * v.y + v.z * v.z + v.w * v.w;
#pragma unroll
  for (int m = 1; m < 64; m <<= 1) { s += __shfl_xor(s, m); s2 += __shfl_xor(s2, m); }
  __shared__ float ps[8];
  const int wid = t >> 6, lane = t & 63;
  if (lane == 0) { ps[wid] = s; ps[wid + 4] = s2; }
  __syncthreads();
  s = ps[0] + ps[1] + ps[2] + ps[3];
  s2 = ps[4] + ps[5] + ps[6] + ps[7];
  float mu = s * (1.f / D_MODEL);
  float rstd = rsqrtf(s2 * (1.f / D_MODEL) - mu * mu + 1e-5f);
  float4 gv = *(const float4*)(g + t * 4);
  float4 bv = *(const float4*)(b + t * 4);
  short4 o;
  o.x = f2bf((v.x - mu) * rstd * gv.x + bv.x);
  o.y = f2bf((v.y - mu) * rstd * gv.y + bv.y);
  o.z = f2bf((v.z - mu) * rstd * gv.z + bv.z);
  o.w = f2bf((v.w - mu) * rstd * gv.w + bv.w);
  *(short4*)(out + (size_t)row * D_MODEL + t * 4) = o;
}

// ---------------- 128x128 bf16 MFMA GEMM, BK=64, swizzled LDS, epilogue by MODE
// A [M][K] bf16 row-major; Bt [N][K] bf16 (B transposed). C = A*B.
// MODE 0: QKV scatter. q,k -> [BH][S][HD] (q scaled by 1/8*log2e); v -> [BH][HD][S]
// MODE 1: C + bias0 + resid -> outf (fp32)
// MODE 2: gelu(C + bias0) -> outb0 (bf16)
// MODE 3: C + bias0 + resid -> outf (fp32)   (resid may alias outf)
template <int MODE>
__global__ __launch_bounds__(256) void gemm128(const short* __restrict__ A,
                                               const short* __restrict__ Bt,
                                               const float* __restrict__ bias0,
                                               const float* __restrict__ bias1,
                                               const float* __restrict__ bias2,
                                               const float* resid, float* outf,
                                               short* outb0, short* outb1, short* outb2,
                                               int M, int N, int K) {
  __shared__ short As[128 * 64];
  __shared__ short Bs[128 * 64];
  const int tid = threadIdx.x;
  const int lane = tid & 63;
  const int wid = tid >> 6;
  const int wr = wid >> 1, wc = wid & 1;
  const int row0 = blockIdx.y * 128, col0 = blockIdx.x * 128;

  f32x4 acc[4][4];
#pragma unroll
  for (int i = 0; i < 4; ++i)
#pragma unroll
    for (int j = 0; j < 4; ++j) acc[i][j] = (f32x4){0.f, 0.f, 0.f, 0.f};

  const int str = tid >> 3;                  // staging row within 32-row group
  const int sch = (tid & 7) ^ (str & 7);     // pre-swizzled source chunk

  for (int k0 = 0; k0 < K; k0 += 64) {
#pragma unroll
    for (int c = 0; c < 4; ++c) {
      int r = c * 32 + str;
      gload16(A + (size_t)(row0 + r) * K + k0 + sch * 8, (char*)As + c * 4096 + tid * 16);
      gload16(Bt + (size_t)(col0 + r) * K + k0 + sch * 8, (char*)Bs + c * 4096 + tid * 16);
    }
    __syncthreads();
#pragma unroll
    for (int kk = 0; kk < 2; ++kk) {
      bf16x8 af[4], bfr[4];
#pragma unroll
      for (int mf = 0; mf < 4; ++mf) {
        int rr = wr * 64 + mf * 16 + (lane & 15);
        int ch = (kk * 4 + (lane >> 4)) ^ (rr & 7);
        af[mf] = *(const bf16x8*)((const char*)As + rr * 128 + ch * 16);
      }
#pragma unroll
      for (int nf = 0; nf < 4; ++nf) {
        int rr = wc * 64 + nf * 16 + (lane & 15);
        int ch = (kk * 4 + (lane >> 4)) ^ (rr & 7);
        bfr[nf] = *(const bf16x8*)((const char*)Bs + rr * 128 + ch * 16);
      }
#pragma unroll
      for (int mf = 0; mf < 4; ++mf)
#pragma unroll
        for (int nf = 0; nf < 4; ++nf)
          acc[mf][nf] = __builtin_amdgcn_mfma_f32_16x16x32_bf16(af[mf], bfr[nf], acc[mf][nf], 0, 0, 0);
    }
    __syncthreads();
  }

#pragma unroll
  for (int mf = 0; mf < 4; ++mf) {
#pragma unroll
    for (int nf = 0; nf < 4; ++nf) {
      const int rowb = row0 + wr * 64 + mf * 16 + ((lane >> 4) << 2);
      const int col = col0 + wc * 64 + nf * 16 + (lane & 15);
      if (MODE == 0) {
        const int which = col >> 10, nn = col & 1023;
        const int hh = nn >> 6, dd = nn & 63;
        const float bias = (which == 0 ? bias0[nn] : which == 1 ? bias1[nn] : bias2[nn]);
        if (which == 2) {
          // V transposed: [BH][HD][SEQ]; 4 consecutive seq -> short4
          const int bb = rowb >> 11, s = rowb & 2047;
          short4 o;
#pragma unroll
          for (int r = 0; r < 4; ++r) {
            float val = acc[mf][nf][r] + bias;
            ((short*)&o)[r] = f2bf(val);
          }
          *(short4*)(outb2 + ((size_t)((bb << 4) + hh) * HD + dd) * SEQ + s) = o;
        } else {
#pragma unroll
          for (int r = 0; r < 4; ++r) {
            const int row = rowb + r;
            float val = acc[mf][nf][r] + bias;
            if (which == 0) val *= 0.18033688011112042f;  // 1/8 * log2(e)
            const int bb = row >> 11, s = row & 2047;
            const size_t dst = (((size_t)((bb << 4) + hh) << 11) + s) * HD + dd;
            (which == 0 ? outb0 : outb1)[dst] = f2bf(val);
          }
        }
      } else {
#pragma unroll
        for (int r = 0; r < 4; ++r) {
          const int row = rowb + r;
          float val = acc[mf][nf][r];
          if (MODE == 2) {
            val += bias0[col];
            float gl = 0.5f * val * (1.f + erff(val * 0.70710678118f));
            outb0[(size_t)row * N + col] = f2bf(gl);
          } else {  // MODE 1 and 3
            val += bias0[col] + resid[(size_t)row * N + col];
            outf[(size_t)row * N + col] = val;
          }
        }
      }
    }
  }
}

// ---------------- flash attention, swapped-QK^T in-register softmax (T12/T13)
// grid (16 qtiles, 64 bh), 256 threads = 4 waves; each wave owns 32 q-rows.
// q,k bf16 [BH][SEQ][HD] (q pre-scaled by 1/8*log2e). vT bf16 [BH][HD][SEQ].
// ctx bf16 [B][SEQ][D] token-major. KVBLK=64, double-buffered K/VT staging.
// S^T = mfma(A=K, B=Q): lane owns full P-row for q = lane&31 (32 keys in regs).
// O^T = mfma(A=V^T, B=P^T): accumulator col = same q -> softmax fully lane-local.
__global__ __launch_bounds__(256) void attn_swp(const short* __restrict__ q,
                                                const short* __restrict__ k,
                                                const short* __restrict__ vT,
                                                short* __restrict__ ctx) {
  __shared__ short Ks[2][4096];   // [64 key][64 d], rows 128B, chunk ^= key&7
  __shared__ short VTs[2][4096];  // [64 d][64 key], rows 128B, chunk ^= d&7
  const int tid = threadIdx.x;
  const int lane = tid & 63;
  const int wid = tid >> 6;
  const int hi = lane >> 5, l31 = lane & 31, l7 = lane & 7;
  const int qt = blockIdx.x, bh = blockIdx.y;
  const size_t base = (size_t)bh * SEQ * HD;  // same extent for vT
  const int q0 = qt * 128 + wid * 32;

  // Q fragments (B-operand): lane -> Q[q0 + l31][ks*16 + hi*8 + j]
  bf16x8 qf[4];
#pragma unroll
  for (int ks = 0; ks < 4; ++ks)
    qf[ks] = *(const bf16x8*)(q + base + (size_t)(q0 + l31) * HD + ks * 16 + hi * 8);

  f32x16 o0 = {0.f}, o1 = {0.f};
#pragma unroll
  for (int r = 0; r < 16; ++r) { o0[r] = 0.f; o1[r] = 0.f; }
  float mreg = -1e30f, lreg = 0.f;

  const int sch = (tid & 7) ^ ((tid >> 3) & 7);  // staging pre-swizzle chunk

  // stage K tile [64][64] and VT tile [64][64] for kv-tile kt into buffer bi
#define STAGE(bi, kt)                                                               \
  {                                                                                 \
    const short* kb_ = k + base + (size_t)(kt) * 64 * HD;                           \
    const short* vb_ = vT + base + (size_t)(kt) * 64;                               \
    _Pragma("unroll") for (int p = 0; p < 2; ++p)                                   \
        gload16(kb_ + (size_t)(p * 32 + (tid >> 3)) * HD + sch * 8,                 \
                Ks[bi] + p * 2048 + tid * 8);                                       \
    _Pragma("unroll") for (int p = 0; p < 2; ++p)                                   \
        gload16(vb_ + (size_t)(p * 32 + (tid >> 3)) * SEQ + sch * 8,                \
                VTs[bi] + p * 2048 + tid * 8);                                      \
  }

  STAGE(0, 0);
  __syncthreads();
  int cur = 0;

  for (int kt = 0; kt < SEQ / 64; ++kt) {
    if (kt + 1 < SEQ / 64) STAGE(cur ^ 1, kt + 1);

    // S^T = K . Q^T : s0 = keys 0..31, s1 = keys 32..63 (x q 0..31)
    f32x16 s0, s1;
#pragma unroll
    for (int r = 0; r < 16; ++r) { s0[r] = 0.f; s1[r] = 0.f; }
#pragma unroll
    for (int ks = 0; ks < 4; ++ks) {
      const int ch = ((ks * 2 + hi) ^ l7) << 3;
      bf16x8 ka0 = *(const bf16x8*)(Ks[cur] + l31 * 64 + ch);
      bf16x8 ka1 = *(const bf16x8*)(Ks[cur] + (32 + l31) * 64 + ch);
      s0 = __builtin_amdgcn_mfma_f32_32x32x16_bf16(ka0, qf[ks], s0, 0, 0, 0);
      s1 = __builtin_amdgcn_mfma_f32_32x32x16_bf16(ka1, qf[ks], s1, 0, 0, 0);
    }

    // row max (lane-local 31 fmax + permlane32_swap merge)
    float pm = s0[0];
#pragma unroll
    for (int r = 1; r < 16; ++r) pm = fmaxf(pm, s0[r]);
#pragma unroll
    for (int r = 0; r < 16; ++r) pm = fmaxf(pm, s1[r]);
    {
      int2v mm = __builtin_amdgcn_permlane32_swap(__builtin_bit_cast(int, pm),
                                                  __builtin_bit_cast(int, pm), false, false);
      pm = fmaxf(__builtin_bit_cast(float, mm[0]), __builtin_bit_cast(float, mm[1]));
    }
    // defer-max (T13): only rescale when max grew by > 8 (log2 domain)
    if (!__all(pm <= mreg + 8.f)) {
      float mn = fmaxf(mreg, pm);
      float al = exp2f(mreg - mn);
      mreg = mn;
      lreg *= al;
#pragma unroll
      for (int r = 0; r < 16; ++r) { o0[r] *= al; o1[r] *= al; }
    }

    // P = exp2(S - m), row sum
    float rs = 0.f;
#pragma unroll
    for (int r = 0; r < 16; ++r) { s0[r] = exp2f(s0[r] - mreg); rs += s0[r]; }
#pragma unroll
    for (int r = 0; r < 16; ++r) { s1[r] = exp2f(s1[r] - mreg); rs += s1[r]; }
    {
      int2v ss = __builtin_amdgcn_permlane32_swap(__builtin_bit_cast(int, rs),
                                                  __builtin_bit_cast(int, rs), false, false);
      rs = __builtin_bit_cast(float, ss[0]) + __builtin_bit_cast(float, ss[1]);
    }
    lreg += rs;

    // pack P -> PV B-operand fragments: per slice s (16 keys): 4 cvt_pk + 2 swaps
    uint4v pw[4];
#pragma unroll
    for (int t = 0; t < 2; ++t) {
#pragma unroll
      for (int ks = 0; ks < 2; ++ks) {
        const f32x16& st = t ? s1 : s0;
        unsigned x0 = cvt_pk_bf16(st[8 * ks + 0], st[8 * ks + 1]);
        unsigned x1 = cvt_pk_bf16(st[8 * ks + 2], st[8 * ks + 3]);
        unsigned y0 = cvt_pk_bf16(st[8 * ks + 4], st[8 * ks + 5]);
        unsigned y1 = cvt_pk_bf16(st[8 * ks + 6], st[8 * ks + 7]);
        int2v a0 = __builtin_amdgcn_permlane32_swap((int)y0, (int)x0, false, false);
        int2v a1 = __builtin_amdgcn_permlane32_swap((int)y1, (int)x1, false, false);
        // a?[1] = w0/w1 (keys j0..j3), a?[0] = w2/w3 (keys j4..j7)
        pw[t * 2 + ks] = (uint4v){(unsigned)a0[1], (unsigned)a1[1],
                                  (unsigned)a0[0], (unsigned)a1[0]};
      }
    }

    // O^T += V^T . P^T  (o0: d 0..31, o1: d 32..63)
#pragma unroll
    for (int s = 0; s < 4; ++s) {
      bf16x8 pf = __builtin_bit_cast(bf16x8, pw[s]);
      const int ch = ((s * 2 + hi) ^ l7) << 3;
      bf16x8 v0 = *(const bf16x8*)(VTs[cur] + l31 * 64 + ch);
      bf16x8 v1 = *(const bf16x8*)(VTs[cur] + (32 + l31) * 64 + ch);
      o0 = __builtin_amdgcn_mfma_f32_32x32x16_bf16(v0, pf, o0, 0, 0, 0);
      o1 = __builtin_amdgcn_mfma_f32_32x32x16_bf16(v1, pf, o1, 0, 0, 0);
    }
    __syncthreads();
    cur ^= 1;
  }
#undef STAGE

  // epilogue: ctx[b][tok][hh*64 + d] = O^T[d][q] / l
  const int b = bh >> 4, hh = bh & 15;
  const float inv = 1.f / lreg;
  const size_t tokoff = ((size_t)(b * SEQ + q0 + l31)) * D_MODEL + hh * HD;
#pragma unroll
  for (int r = 0; r < 16; ++r) {
    const int d = (r & 3) + 8 * (r >> 2) + 4 * hi;
    ctx[tokoff + d] = f2bf(o0[r] * inv);
    ctx[tokoff + 32 + d] = f2bf(o1[r] * inv);
  }
}

// ---------------- launcher
extern "C" void kernel_launch(void* const* d_in, const int* in_sizes, int n_in,
                              void* d_out, int out_size, void* d_ws, size_t ws_size,
                              hipStream_t stream) {
  const float* x  = (const float*)d_in[0];
  const float* Wq = (const float*)d_in[1];
  const float* bq = (const float*)d_in[2];
  const float* Wk = (const float*)d_in[3];
  const float* bk = (const float*)d_in[4];
  const float* Wv = (const float*)d_in[5];
  const float* bv = (const float*)d_in[6];
  const float* Wo = (const float*)d_in[7];
  const float* bo = (const float*)d_in[8];
  const float* g1 = (const float*)d_in[9];
  const float* b1 = (const float*)d_in[10];
  const float* g2 = (const float*)d_in[11];
  const float* b2 = (const float*)d_in[12];
  const float* W1 = (const float*)d_in[13];
  const float* bf1 = (const float*)d_in[14];
  const float* W2 = (const float*)d_in[15];
  const float* bf2 = (const float*)d_in[16];

  char* w = (char*)d_ws;
  short* WqkvT = (short*)w; w += (size_t)3072 * 1024 * 2;      // 6 MB
  short* WoT   = (short*)w; w += (size_t)1024 * 1024 * 2;      // 2 MB
  short* W1T   = (short*)w; w += (size_t)2048 * 1024 * 2;      // 4 MB
  short* W2T   = (short*)w; w += (size_t)1024 * 2048 * 2;      // 4 MB
  short* xn    = (short*)w; w += (size_t)M_TOK * 1024 * 2;     // 16 MB
  short* qb    = (short*)w; w += (size_t)M_TOK * 1024 * 2;
  short* kb    = (short*)w; w += (size_t)M_TOK * 1024 * 2;
  short* vTb   = (short*)w; w += (size_t)M_TOK * 1024 * 2;     // [BH][HD][SEQ]
  short* ctxb  = (short*)w; w += (size_t)M_TOK * 1024 * 2;
  short* xn2   = (short*)w; w += (size_t)M_TOK * 1024 * 2;
  short* hb    = (short*)w; w += (size_t)M_TOK * 2048 * 2;     // 32 MB

  dim3 blk(256);

  // weights -> bf16 transposed
  transpose_cast<<<dim3(16, 16), blk, 0, stream>>>(Wq, WqkvT, 1024, 1024);
  transpose_cast<<<dim3(16, 16), blk, 0, stream>>>(Wk, WqkvT + 1024 * 1024, 1024, 1024);
  transpose_cast<<<dim3(16, 16), blk, 0, stream>>>(Wv, WqkvT + 2 * 1024 * 1024, 1024, 1024);
  transpose_cast<<<dim3(16, 16), blk, 0, stream>>>(Wo, WoT, 1024, 1024);
  transpose_cast<<<dim3(32, 16), blk, 0, stream>>>(W1, W1T, 1024, 2048);
  transpose_cast<<<dim3(16, 32), blk, 0, stream>>>(W2, W2T, 2048, 1024);

  // LN1
  ln_bf16<<<M_TOK, blk, 0, stream>>>(x, g1, b1, xn);

  // QKV projection (fused 3072-wide GEMM, scatter q/k head-major, v transposed)
  gemm128<0><<<dim3(24, 64), blk, 0, stream>>>(xn, WqkvT, bq, bk, bv,
                                               nullptr, nullptr, qb, kb, vTb,
                                               M_TOK, 3072, 1024);

  // attention (swapped-QK^T, in-register softmax)
  attn_swp<<<dim3(16, 64), blk, 0, stream>>>(qb, kb, vTb, ctxb);

  // out proj + residual -> d_out (fp32 x2)
  gemm128<1><<<dim3(8, 64), blk, 0, stream>>>(ctxb, WoT, bo, nullptr, nullptr,
                                              x, (float*)d_out, nullptr, nullptr, nullptr,
                                              M_TOK, 1024, 1024);

  // LN2 on x2
  ln_bf16<<<M_TOK, blk, 0, stream>>>((const float*)d_out, g2, b2, xn2);

  // FFN1 + GELU
  gemm128<2><<<dim3(16, 64), blk, 0, stream>>>(xn2, W1T, bf1, nullptr, nullptr,
                                               nullptr, nullptr, hb, nullptr, nullptr,
                                               M_TOK, 2048, 1024);

  // FFN2 + residual (in-place on d_out)
  gemm128<3><<<dim3(8, 64), blk, 0, stream>>>(hb, W2T, bf2, nullptr, nullptr,
                                              (const float*)d_out, (float*)d_out,
                                              nullptr, nullptr, nullptr,
                                              M_TOK, 1024, 2048);
}

// Round 4
// 368.192 us; speedup vs baseline: 1.3400x; 1.0361x over previous
//
#include <hip/hip_runtime.h>
#include <hip/hip_bf16.h>
#include <math.h>

#define D_MODEL 1024
#define H_NUM 16
#define HD 64
#define FF_DIM 2048
#define SEQ 2048
#define BATCH 4
#define M_TOK 8192  // BATCH*SEQ

typedef __attribute__((ext_vector_type(8))) short bf16x8;
typedef __attribute__((ext_vector_type(4))) float f32x4;
typedef __attribute__((ext_vector_type(16))) float f32x16;
typedef __attribute__((ext_vector_type(4))) unsigned int uint4v;
typedef __attribute__((ext_vector_type(2))) int int2v;

__device__ __forceinline__ short f2bf(float f) {
  __hip_bfloat16 h = __float2bfloat16(f);
  return *reinterpret_cast<short*>(&h);
}

__device__ __forceinline__ void gload16(const void* g, void* l) {
  __builtin_amdgcn_global_load_lds((const __attribute__((address_space(1))) void*)g,
                                   (__attribute__((address_space(3))) void*)l, 16, 0, 0);
}

__device__ __forceinline__ unsigned cvt_pk_bf16(float lo, float hi) {
  unsigned r;
  asm("v_cvt_pk_bf16_f32 %0, %1, %2" : "=v"(r) : "v"(lo), "v"(hi));
  return r;
}

#define BARRIER() __builtin_amdgcn_s_barrier()
#define LGKM0()                                  \
  do {                                           \
    asm volatile("s_waitcnt lgkmcnt(0)");        \
    __builtin_amdgcn_sched_barrier(0);           \
  } while (0)
#define VMC(n)                                   \
  do {                                           \
    asm volatile("s_waitcnt vmcnt(" #n ")");     \
    __builtin_amdgcn_sched_barrier(0);           \
  } while (0)

// ---------------- weight transpose + cast: src fp32 [K][N] -> dst bf16 [N][K]
__global__ __launch_bounds__(256) void transpose_cast(const float* __restrict__ src,
                                                      short* __restrict__ dst,
                                                      int K, int N) {
  __shared__ float tile[64][65];
  const int n0 = blockIdx.x * 64, k0 = blockIdx.y * 64;
  const int tr = threadIdx.x >> 4;         // 0..15
  const int tc = (threadIdx.x & 15) * 4;   // 0..60
#pragma unroll
  for (int i = 0; i < 4; ++i) {
    int kr = tr + i * 16;
    float4 v = *(const float4*)(src + (size_t)(k0 + kr) * N + n0 + tc);
    tile[kr][tc] = v.x; tile[kr][tc + 1] = v.y; tile[kr][tc + 2] = v.z; tile[kr][tc + 3] = v.w;
  }
  __syncthreads();
#pragma unroll
  for (int i = 0; i < 4; ++i) {
    int r = tr + i * 16;
    short4 o;
    o.x = f2bf(tile[tc][r]);
    o.y = f2bf(tile[tc + 1][r]);
    o.z = f2bf(tile[tc + 2][r]);
    o.w = f2bf(tile[tc + 3][r]);
    *(short4*)(dst + (size_t)(n0 + r) * K + k0 + tc) = o;
  }
}

// ---------------- LayerNorm fp32 [rows][1024] -> bf16, one block per row
__global__ __launch_bounds__(256) void ln_bf16(const float* __restrict__ x,
                                               const float* __restrict__ g,
                                               const float* __restrict__ b,
                                               short* __restrict__ out) {
  const int row = blockIdx.x;
  const int t = threadIdx.x;
  const float* xr = x + (size_t)row * D_MODEL;
  float4 v = *(const float4*)(xr + t * 4);
  float s = v.x + v.y + v.z + v.w;
  float s2 = v.x * v.x + v.y * v.y + v.z * v.z + v.w * v.w;
#pragma unroll
  for (int m = 1; m < 64; m <<= 1) { s += __shfl_xor(s, m); s2 += __shfl_xor(s2, m); }
  __shared__ float ps[8];
  const int wid = t >> 6, lane = t & 63;
  if (lane == 0) { ps[wid] = s; ps[wid + 4] = s2; }
  __syncthreads();
  s = ps[0] + ps[1] + ps[2] + ps[3];
  s2 = ps[4] + ps[5] + ps[6] + ps[7];
  float mu = s * (1.f / D_MODEL);
  float rstd = rsqrtf(s2 * (1.f / D_MODEL) - mu * mu + 1e-5f);
  float4 gv = *(const float4*)(g + t * 4);
  float4 bv = *(const float4*)(b + t * 4);
  short4 o;
  o.x = f2bf((v.x - mu) * rstd * gv.x + bv.x);
  o.y = f2bf((v.y - mu) * rstd * gv.y + bv.y);
  o.z = f2bf((v.z - mu) * rstd * gv.z + bv.z);
  o.w = f2bf((v.w - mu) * rstd * gv.w + bv.w);
  *(short4*)(out + (size_t)row * D_MODEL + t * 4) = o;
}

// ---------------- 8-phase BMx256 bf16 MFMA GEMM (T1+T2+T3+T4+T5), BK=64
// 512 threads = 8 waves (2M x 4N). Per-wave C: (BM/2) x 64.
// K-tile split into two K=32 halves; per phase: ds_read subtile + stage half
// + barrier + lgkmcnt(0) + setprio(1) + MFMA cluster + setprio(0) + barrier.
// Counted vmcnt (never 0 mid-loop): 2 half-tiles in flight.
// A [M][K] bf16 row-major; Bt [N][K] bf16. C = A*B.
// MODE 0: QKV scatter. q,k -> [BH][S][HD] (q scaled by 1/8*log2e); v -> [BH][HD][S]
// MODE 1/3: C + bias0 + resid -> outf (fp32)
// MODE 2: gelu(C + bias0) -> outb0 (bf16)
template <int BM, int MODE>
__global__ __launch_bounds__(512, 2) void gemm8p(const short* __restrict__ A,
                                                 const short* __restrict__ Bt,
                                                 const float* __restrict__ bias0,
                                                 const float* __restrict__ bias1,
                                                 const float* __restrict__ bias2,
                                                 const float* resid, float* outf,
                                                 short* outb0, short* outb1, short* outb2,
                                                 int M, int N, int K) {
  constexpr int FM = BM / 32;          // A frags per wave (4 or 8)
  constexpr int HM = FM / 2;           // A frags per phase
  constexpr int GA = BM / 128;         // gloads per A half-tile (1 or 2)
  constexpr int GB = 2;                // gloads per B half-tile
  constexpr int ABUF = BM * 64;        // shorts per A buffer (2 khalves)
  constexpr int BBUF = 256 * 64;
  constexpr int BUFS = ABUF + BBUF;
  __shared__ short lds[2 * BUFS];

  const int tid = threadIdx.x;
  const int lane = tid & 63;
  const int wid = tid >> 6;
  const int wr = wid >> 2, wc = wid & 3;
  const int l15 = lane & 15, l4 = lane >> 4;

  // XCD-bijective block swizzle (grid sizes are multiples of 8)
  const int nwg = gridDim.x;
  const int id = blockIdx.x;
  const int swz = (id & 7) * (nwg >> 3) + (id >> 3);
  const int nbx = N >> 8;
  const int by = swz / nbx, bx = swz - by * nbx;
  const int row0 = by * BM, col0 = bx * 256;

  f32x4 acc[FM][4];
#pragma unroll
  for (int i = 0; i < FM; ++i)
#pragma unroll
    for (int j = 0; j < 4; ++j) acc[i][j] = (f32x4){0.f, 0.f, 0.f, 0.f};

  const int NT = K >> 6;

  // stage one K-half (A half + B half) of tile t into buffer `buf`
  auto STAGE = [&](int buf, int t, int kh) {
    const int k0 = t * 64 + kh * 32;
    short* ab = lds + buf * BUFS + kh * (BM * 32);
#pragma unroll
    for (int s = 0; s < GA; ++s) {
      const int r = s * 128 + (tid >> 2);
      const int g = (tid & 3) ^ ((r >> 1) & 3);
      gload16(A + (size_t)(row0 + r) * K + k0 + g * 8, ab + s * 4096 + tid * 8);
    }
    short* bb = lds + buf * BUFS + ABUF + kh * (256 * 32);
#pragma unroll
    for (int s = 0; s < GB; ++s) {
      const int r = s * 128 + (tid >> 2);
      const int g = (tid & 3) ^ ((r >> 1) & 3);
      gload16(Bt + (size_t)(col0 + r) * K + k0 + g * 8, bb + s * 4096 + tid * 8);
    }
  };

  auto LDA = [&](bf16x8* dst, int buf, int kh, int h) {
    const short* ab = lds + buf * BUFS + kh * (BM * 32);
#pragma unroll
    for (int i = 0; i < HM; ++i) {
      const int R = wr * (BM / 2) + (h * HM + i) * 16 + l15;
      dst[i] = *(const bf16x8*)(ab + R * 32 + ((l4 ^ ((R >> 1) & 3)) << 3));
    }
  };
  auto LDB = [&](bf16x8* dst, int buf, int kh) {
    const short* bb = lds + buf * BUFS + ABUF + kh * (256 * 32);
#pragma unroll
    for (int nf = 0; nf < 4; ++nf) {
      const int R = wc * 64 + nf * 16 + l15;
      dst[nf] = *(const bf16x8*)(bb + R * 32 + ((l4 ^ ((R >> 1) & 3)) << 3));
    }
  };

  bf16x8 Af[HM], Bf[4];

  // prologue: both halves of tile 0
  STAGE(0, 0, 0);
  STAGE(0, 0, 1);
  if (GA == 1) { VMC(3); } else { VMC(4); }
  BARRIER();

  for (int t = 0; t < NT; ++t) {
    const int b = t & 1;
    const bool nst = (t + 1 < NT);

#pragma unroll
    for (int kh = 0; kh < 2; ++kh) {
      // phase A: first M-half + B frags for this k-half
      LDA(Af, b, kh, 0);
      LDB(Bf, b, kh);
      if (nst) STAGE(b ^ 1, t + 1, kh);
      BARRIER();
      LGKM0();
      __builtin_amdgcn_s_setprio(1);
#pragma unroll
      for (int i = 0; i < HM; ++i)
#pragma unroll
        for (int nf = 0; nf < 4; ++nf)
          acc[i][nf] = __builtin_amdgcn_mfma_f32_16x16x32_bf16(Af[i], Bf[nf], acc[i][nf], 0, 0, 0);
      __builtin_amdgcn_s_setprio(0);
      BARRIER();

      // phase B: second M-half (reuse B frags)
      LDA(Af, b, kh, 1);
      BARRIER();
      LGKM0();
      __builtin_amdgcn_s_setprio(1);
#pragma unroll
      for (int i = 0; i < HM; ++i)
#pragma unroll
        for (int nf = 0; nf < 4; ++nf)
          acc[HM + i][nf] =
              __builtin_amdgcn_mfma_f32_16x16x32_bf16(Af[i], Bf[nf], acc[HM + i][nf], 0, 0, 0);
      __builtin_amdgcn_s_setprio(0);
      if (kh == 0) {
        // k1(t) must be landed before next phase's ds_reads
        if (nst) {
          if (GA == 1) { VMC(3); } else { VMC(4); }
        } else {
          VMC(0);
        }
      } else {
        // k0(t+1) must be landed before next tile's first phase
        if (GA == 1) { VMC(3); } else { VMC(4); }
      }
      BARRIER();
    }
  }

  // epilogue
#pragma unroll
  for (int mf = 0; mf < FM; ++mf) {
#pragma unroll
    for (int nf = 0; nf < 4; ++nf) {
      const int rowb = row0 + wr * (BM / 2) + mf * 16 + (l4 << 2);
      const int col = col0 + wc * 64 + nf * 16 + l15;
      if (MODE == 0) {
        const int which = col >> 10, nn = col & 1023;
        const int hh = nn >> 6, dd = nn & 63;
        const float bias = (which == 0 ? bias0[nn] : which == 1 ? bias1[nn] : bias2[nn]);
        if (which == 2) {
          // V transposed: [BH][HD][SEQ]; 4 consecutive seq -> short4
          const int bb = rowb >> 11, s = rowb & 2047;
          short4 o;
#pragma unroll
          for (int r = 0; r < 4; ++r) {
            float val = acc[mf][nf][r] + bias;
            ((short*)&o)[r] = f2bf(val);
          }
          *(short4*)(outb2 + ((size_t)((bb << 4) + hh) * HD + dd) * SEQ + s) = o;
        } else {
#pragma unroll
          for (int r = 0; r < 4; ++r) {
            const int row = rowb + r;
            float val = acc[mf][nf][r] + bias;
            if (which == 0) val *= 0.18033688011112042f;  // 1/8 * log2(e)
            const int bb = row >> 11, s = row & 2047;
            const size_t dst = (((size_t)((bb << 4) + hh) << 11) + s) * HD + dd;
            (which == 0 ? outb0 : outb1)[dst] = f2bf(val);
          }
        }
      } else {
#pragma unroll
        for (int r = 0; r < 4; ++r) {
          const int row = rowb + r;
          float val = acc[mf][nf][r];
          if (MODE == 2) {
            val += bias0[col];
            float gl = 0.5f * val * (1.f + erff(val * 0.70710678118f));
            outb0[(size_t)row * N + col] = f2bf(gl);
          } else {  // MODE 1 and 3
            val += bias0[col] + resid[(size_t)row * N + col];
            outf[(size_t)row * N + col] = val;
          }
        }
      }
    }
  }
}

// ---------------- flash attention, swapped-QK^T in-register softmax (T12/T13)
// grid (16 qtiles, 64 bh), 256 threads = 4 waves; each wave owns 32 q-rows.
// q,k bf16 [BH][SEQ][HD] (q pre-scaled by 1/8*log2e). vT bf16 [BH][HD][SEQ].
// ctx bf16 [B][SEQ][D] token-major. KVBLK=64, double-buffered K/VT staging.
__global__ __launch_bounds__(256) void attn_swp(const short* __restrict__ q,
                                                const short* __restrict__ k,
                                                const short* __restrict__ vT,
                                                short* __restrict__ ctx) {
  __shared__ short Ks[2][4096];   // [64 key][64 d], rows 128B, chunk ^= key&7
  __shared__ short VTs[2][4096];  // [64 d][64 key], rows 128B, chunk ^= d&7
  const int tid = threadIdx.x;
  const int lane = tid & 63;
  const int wid = tid >> 6;
  const int hi = lane >> 5, l31 = lane & 31, l7 = lane & 7;
  const int qt = blockIdx.x, bh = blockIdx.y;
  const size_t base = (size_t)bh * SEQ * HD;  // same extent for vT
  const int q0 = qt * 128 + wid * 32;

  // Q fragments (B-operand): lane -> Q[q0 + l31][ks*16 + hi*8 + j]
  bf16x8 qf[4];
#pragma unroll
  for (int ks = 0; ks < 4; ++ks)
    qf[ks] = *(const bf16x8*)(q + base + (size_t)(q0 + l31) * HD + ks * 16 + hi * 8);

  f32x16 o0 = {0.f}, o1 = {0.f};
#pragma unroll
  for (int r = 0; r < 16; ++r) { o0[r] = 0.f; o1[r] = 0.f; }
  float mreg = -1e30f, lreg = 0.f;

  const int sch = (tid & 7) ^ ((tid >> 3) & 7);  // staging pre-swizzle chunk

#define STAGE_AT(bi, kt)                                                            \
  {                                                                                 \
    const short* kb_ = k + base + (size_t)(kt) * 64 * HD;                           \
    const short* vb_ = vT + base + (size_t)(kt) * 64;                               \
    _Pragma("unroll") for (int p = 0; p < 2; ++p)                                   \
        gload16(kb_ + (size_t)(p * 32 + (tid >> 3)) * HD + sch * 8,                 \
                Ks[bi] + p * 2048 + tid * 8);                                       \
    _Pragma("unroll") for (int p = 0; p < 2; ++p)                                   \
        gload16(vb_ + (size_t)(p * 32 + (tid >> 3)) * SEQ + sch * 8,                \
                VTs[bi] + p * 2048 + tid * 8);                                      \
  }

  STAGE_AT(0, 0);
  __syncthreads();
  int cur = 0;

  for (int kt = 0; kt < SEQ / 64; ++kt) {
    if (kt + 1 < SEQ / 64) STAGE_AT(cur ^ 1, kt + 1);

    // S^T = K . Q^T : s0 = keys 0..31, s1 = keys 32..63 (x q 0..31)
    f32x16 s0, s1;
#pragma unroll
    for (int r = 0; r < 16; ++r) { s0[r] = 0.f; s1[r] = 0.f; }
#pragma unroll
    for (int ks = 0; ks < 4; ++ks) {
      const int ch = ((ks * 2 + hi) ^ l7) << 3;
      bf16x8 ka0 = *(const bf16x8*)(Ks[cur] + l31 * 64 + ch);
      bf16x8 ka1 = *(const bf16x8*)(Ks[cur] + (32 + l31) * 64 + ch);
      s0 = __builtin_amdgcn_mfma_f32_32x32x16_bf16(ka0, qf[ks], s0, 0, 0, 0);
      s1 = __builtin_amdgcn_mfma_f32_32x32x16_bf16(ka1, qf[ks], s1, 0, 0, 0);
    }

    // row max (lane-local fmax + permlane32_swap merge)
    float pm = s0[0];
#pragma unroll
    for (int r = 1; r < 16; ++r) pm = fmaxf(pm, s0[r]);
#pragma unroll
    for (int r = 0; r < 16; ++r) pm = fmaxf(pm, s1[r]);
    {
      int2v mm = __builtin_amdgcn_permlane32_swap(__builtin_bit_cast(int, pm),
                                                  __builtin_bit_cast(int, pm), false, false);
      pm = fmaxf(__builtin_bit_cast(float, mm[0]), __builtin_bit_cast(float, mm[1]));
    }
    // defer-max (T13): only rescale when max grew by > 8 (log2 domain)
    if (!__all(pm <= mreg + 8.f)) {
      float mn = fmaxf(mreg, pm);
      float al = exp2f(mreg - mn);
      mreg = mn;
      lreg *= al;
#pragma unroll
      for (int r = 0; r < 16; ++r) { o0[r] *= al; o1[r] *= al; }
    }

    // P = exp2(S - m), row sum
    float rs = 0.f;
#pragma unroll
    for (int r = 0; r < 16; ++r) { s0[r] = exp2f(s0[r] - mreg); rs += s0[r]; }
#pragma unroll
    for (int r = 0; r < 16; ++r) { s1[r] = exp2f(s1[r] - mreg); rs += s1[r]; }
    {
      int2v ss = __builtin_amdgcn_permlane32_swap(__builtin_bit_cast(int, rs),
                                                  __builtin_bit_cast(int, rs), false, false);
      rs = __builtin_bit_cast(float, ss[0]) + __builtin_bit_cast(float, ss[1]);
    }
    lreg += rs;

    // pack P -> PV B-operand fragments: per 16-key slice: 4 cvt_pk + 2 swaps
    uint4v pw[4];
#pragma unroll
    for (int t = 0; t < 2; ++t) {
#pragma unroll
      for (int ks = 0; ks < 2; ++ks) {
        const f32x16& st = t ? s1 : s0;
        unsigned x0 = cvt_pk_bf16(st[8 * ks + 0], st[8 * ks + 1]);
        unsigned x1 = cvt_pk_bf16(st[8 * ks + 2], st[8 * ks + 3]);
        unsigned y0 = cvt_pk_bf16(st[8 * ks + 4], st[8 * ks + 5]);
        unsigned y1 = cvt_pk_bf16(st[8 * ks + 6], st[8 * ks + 7]);
        int2v a0 = __builtin_amdgcn_permlane32_swap((int)y0, (int)x0, false, false);
        int2v a1 = __builtin_amdgcn_permlane32_swap((int)y1, (int)x1, false, false);
        pw[t * 2 + ks] = (uint4v){(unsigned)a0[1], (unsigned)a1[1],
                                  (unsigned)a0[0], (unsigned)a1[0]};
      }
    }

    // O^T += V^T . P^T  (o0: d 0..31, o1: d 32..63)
#pragma unroll
    for (int s = 0; s < 4; ++s) {
      bf16x8 pf = __builtin_bit_cast(bf16x8, pw[s]);
      const int ch = ((s * 2 + hi) ^ l7) << 3;
      bf16x8 v0 = *(const bf16x8*)(VTs[cur] + l31 * 64 + ch);
      bf16x8 v1 = *(const bf16x8*)(VTs[cur] + (32 + l31) * 64 + ch);
      o0 = __builtin_amdgcn_mfma_f32_32x32x16_bf16(v0, pf, o0, 0, 0, 0);
      o1 = __builtin_amdgcn_mfma_f32_32x32x16_bf16(v1, pf, o1, 0, 0, 0);
    }
    __syncthreads();
    cur ^= 1;
  }
#undef STAGE_AT

  // epilogue: ctx[b][tok][hh*64 + d] = O^T[d][q] / l
  const int b = bh >> 4, hh = bh & 15;
  const float inv = 1.f / lreg;
  const size_t tokoff = ((size_t)(b * SEQ + q0 + l31)) * D_MODEL + hh * HD;
#pragma unroll
  for (int r = 0; r < 16; ++r) {
    const int d = (r & 3) + 8 * (r >> 2) + 4 * hi;
    ctx[tokoff + d] = f2bf(o0[r] * inv);
    ctx[tokoff + 32 + d] = f2bf(o1[r] * inv);
  }
}

// ---------------- launcher
extern "C" void kernel_launch(void* const* d_in, const int* in_sizes, int n_in,
                              void* d_out, int out_size, void* d_ws, size_t ws_size,
                              hipStream_t stream) {
  const float* x  = (const float*)d_in[0];
  const float* Wq = (const float*)d_in[1];
  const float* bq = (const float*)d_in[2];
  const float* Wk = (const float*)d_in[3];
  const float* bk = (const float*)d_in[4];
  const float* Wv = (const float*)d_in[5];
  const float* bv = (const float*)d_in[6];
  const float* Wo = (const float*)d_in[7];
  const float* bo = (const float*)d_in[8];
  const float* g1 = (const float*)d_in[9];
  const float* b1 = (const float*)d_in[10];
  const float* g2 = (const float*)d_in[11];
  const float* b2 = (const float*)d_in[12];
  const float* W1 = (const float*)d_in[13];
  const float* bf1 = (const float*)d_in[14];
  const float* W2 = (const float*)d_in[15];
  const float* bf2 = (const float*)d_in[16];

  char* w = (char*)d_ws;
  short* WqkvT = (short*)w; w += (size_t)3072 * 1024 * 2;      // 6 MB
  short* WoT   = (short*)w; w += (size_t)1024 * 1024 * 2;      // 2 MB
  short* W1T   = (short*)w; w += (size_t)2048 * 1024 * 2;      // 4 MB
  short* W2T   = (short*)w; w += (size_t)1024 * 2048 * 2;      // 4 MB
  short* xn    = (short*)w; w += (size_t)M_TOK * 1024 * 2;     // 16 MB
  short* qb    = (short*)w; w += (size_t)M_TOK * 1024 * 2;
  short* kb    = (short*)w; w += (size_t)M_TOK * 1024 * 2;
  short* vTb   = (short*)w; w += (size_t)M_TOK * 1024 * 2;     // [BH][HD][SEQ]
  short* ctxb  = (short*)w; w += (size_t)M_TOK * 1024 * 2;
  short* xn2   = (short*)w; w += (size_t)M_TOK * 1024 * 2;
  short* hb    = (short*)w; w += (size_t)M_TOK * 2048 * 2;     // 32 MB

  dim3 blk(256);

  // weights -> bf16 transposed
  transpose_cast<<<dim3(16, 16), blk, 0, stream>>>(Wq, WqkvT, 1024, 1024);
  transpose_cast<<<dim3(16, 16), blk, 0, stream>>>(Wk, WqkvT + 1024 * 1024, 1024, 1024);
  transpose_cast<<<dim3(16, 16), blk, 0, stream>>>(Wv, WqkvT + 2 * 1024 * 1024, 1024, 1024);
  transpose_cast<<<dim3(16, 16), blk, 0, stream>>>(Wo, WoT, 1024, 1024);
  transpose_cast<<<dim3(32, 16), blk, 0, stream>>>(W1, W1T, 1024, 2048);
  transpose_cast<<<dim3(16, 32), blk, 0, stream>>>(W2, W2T, 2048, 1024);

  // LN1
  ln_bf16<<<M_TOK, blk, 0, stream>>>(x, g1, b1, xn);

  // QKV projection (fused 3072-wide GEMM, scatter q/k head-major, v transposed)
  gemm8p<256, 0><<<dim3(12 * 32), dim3(512), 0, stream>>>(
      xn, WqkvT, bq, bk, bv, nullptr, nullptr, qb, kb, vTb, M_TOK, 3072, 1024);

  // attention (swapped-QK^T, in-register softmax)
  attn_swp<<<dim3(16, 64), blk, 0, stream>>>(qb, kb, vTb, ctxb);

  // out proj + residual -> d_out (fp32 x2)
  gemm8p<128, 1><<<dim3(4 * 64), dim3(512), 0, stream>>>(
      ctxb, WoT, bo, nullptr, nullptr, x, (float*)d_out, nullptr, nullptr, nullptr,
      M_TOK, 1024, 1024);

  // LN2 on x2
  ln_bf16<<<M_TOK, blk, 0, stream>>>((const float*)d_out, g2, b2, xn2);

  // FFN1 + GELU
  gemm8p<256, 2><<<dim3(8 * 32), dim3(512), 0, stream>>>(
      xn2, W1T, bf1, nullptr, nullptr, nullptr, nullptr, hb, nullptr, nullptr,
      M_TOK, 2048, 1024);

  // FFN2 + residual (in-place on d_out)
  gemm8p<128, 3><<<dim3(4 * 64), dim3(512), 0, stream>>>(
      hb, W2T, bf2, nullptr, nullptr, (const float*)d_out, (float*)d_out,
      nullptr, nullptr, nullptr, M_TOK, 1024, 2048);
}

// Round 5
// 337.262 us; speedup vs baseline: 1.4629x; 1.0917x over previous
//
#include <hip/hip_runtime.h>
#include <hip/hip_bf16.h>
#include <math.h>

#define D_MODEL 1024
#define H_NUM 16
#define HD 64
#define FF_DIM 2048
#define SEQ 2048
#define BATCH 4
#define M_TOK 8192  // BATCH*SEQ

typedef __attribute__((ext_vector_type(8))) short bf16x8;
typedef __attribute__((ext_vector_type(4))) float f32x4;
typedef __attribute__((ext_vector_type(16))) float f32x16;
typedef __attribute__((ext_vector_type(4))) unsigned int uint4v;
typedef __attribute__((ext_vector_type(2))) int int2v;

__device__ __forceinline__ short f2bf(float f) {
  __hip_bfloat16 h = __float2bfloat16(f);
  return *reinterpret_cast<short*>(&h);
}

__device__ __forceinline__ void gload16(const void* g, void* l) {
  __builtin_amdgcn_global_load_lds((const __attribute__((address_space(1))) void*)g,
                                   (__attribute__((address_space(3))) void*)l, 16, 0, 0);
}

__device__ __forceinline__ unsigned cvt_pk_bf16(float lo, float hi) {
  unsigned r;
  asm("v_cvt_pk_bf16_f32 %0, %1, %2" : "=v"(r) : "v"(lo), "v"(hi));
  return r;
}

// raw v_exp_f32 (2^x). Safe here: args <= ~8; tiny args flush to 0 (fine for softmax).
__device__ __forceinline__ float fexp2(float x) {
  float r;
  asm("v_exp_f32 %0, %1" : "=v"(r) : "v"(x));
  return r;
}

__device__ __forceinline__ float fmax3(float a, float b, float c) {
  float r;
  asm("v_max3_f32 %0, %1, %2, %3" : "=v"(r) : "v"(a), "v"(b), "v"(c));
  return r;
}

#define BARRIER() __builtin_amdgcn_s_barrier()
#define LGKM0()                                  \
  do {                                           \
    asm volatile("s_waitcnt lgkmcnt(0)");        \
    __builtin_amdgcn_sched_barrier(0);           \
  } while (0)
#define VMC(n)                                   \
  do {                                           \
    asm volatile("s_waitcnt vmcnt(" #n ")");     \
    __builtin_amdgcn_sched_barrier(0);           \
  } while (0)

// ---------------- all weight transposes fused: fp32 [K][N] -> bf16 [N][K]
__global__ __launch_bounds__(256) void transpose_all(
    const float* __restrict__ Wq, const float* __restrict__ Wk,
    const float* __restrict__ Wv, const float* __restrict__ Wo,
    const float* __restrict__ W1, const float* __restrict__ W2,
    short* __restrict__ WqkvT, short* __restrict__ WoT,
    short* __restrict__ W1T, short* __restrict__ W2T) {
  const int bid = blockIdx.x;
  const float* src;
  short* dst;
  int K, N, t;
  if (bid < 256)       { src = Wq; dst = WqkvT;           K = 1024; N = 1024; t = bid; }
  else if (bid < 512)  { src = Wk; dst = WqkvT + 1048576; K = 1024; N = 1024; t = bid - 256; }
  else if (bid < 768)  { src = Wv; dst = WqkvT + 2097152; K = 1024; N = 1024; t = bid - 512; }
  else if (bid < 1024) { src = Wo; dst = WoT;             K = 1024; N = 1024; t = bid - 768; }
  else if (bid < 1536) { src = W1; dst = W1T;             K = 1024; N = 2048; t = bid - 1024; }
  else                 { src = W2; dst = W2T;             K = 2048; N = 1024; t = bid - 1536; }
  const int lg = (N == 2048) ? 5 : 4;
  const int ty = t >> lg, tx = t & ((1 << lg) - 1);
  const int n0 = tx * 64, k0 = ty * 64;

  __shared__ float tile[64][65];
  const int tr = threadIdx.x >> 4;
  const int tc = (threadIdx.x & 15) * 4;
#pragma unroll
  for (int i = 0; i < 4; ++i) {
    int kr = tr + i * 16;
    float4 v = *(const float4*)(src + (size_t)(k0 + kr) * N + n0 + tc);
    tile[kr][tc] = v.x; tile[kr][tc + 1] = v.y; tile[kr][tc + 2] = v.z; tile[kr][tc + 3] = v.w;
  }
  __syncthreads();
#pragma unroll
  for (int i = 0; i < 4; ++i) {
    int r = tr + i * 16;
    short4 o;
    o.x = f2bf(tile[tc][r]);
    o.y = f2bf(tile[tc + 1][r]);
    o.z = f2bf(tile[tc + 2][r]);
    o.w = f2bf(tile[tc + 3][r]);
    *(short4*)(dst + (size_t)(n0 + r) * K + k0 + tc) = o;
  }
}

// ---------------- V transpose: [BH][SEQ][HD] bf16 -> [BH][HD][SEQ]
__global__ __launch_bounds__(256) void transpose_v(const short* __restrict__ src,
                                                   short* __restrict__ dst) {
  __shared__ short t[64][72];
  const int s0 = blockIdx.x * 64;
  const size_t b = (size_t)blockIdx.y * SEQ * HD;
  const int r = threadIdx.x >> 2;          // seq row 0..63
  const int c = (threadIdx.x & 3) * 16;    // d col 0/16/32/48
  *(bf16x8*)&t[r][c] = *(const bf16x8*)(src + b + (size_t)(s0 + r) * HD + c);
  *(bf16x8*)&t[r][c + 8] = *(const bf16x8*)(src + b + (size_t)(s0 + r) * HD + c + 8);
  __syncthreads();
  const int d = threadIdx.x >> 2;          // d row 0..63
  const int cc = (threadIdx.x & 3) * 16;   // seq chunk
  bf16x8 o0, o1;
#pragma unroll
  for (int i = 0; i < 8; ++i) o0[i] = t[cc + i][d];
#pragma unroll
  for (int i = 0; i < 8; ++i) o1[i] = t[cc + 8 + i][d];
  *(bf16x8*)(dst + b + (size_t)d * SEQ + s0 + cc) = o0;
  *(bf16x8*)(dst + b + (size_t)d * SEQ + s0 + cc + 8) = o1;
}

// ---------------- LayerNorm fp32 [rows][1024] -> bf16, one block per row
__global__ __launch_bounds__(256) void ln_bf16(const float* __restrict__ x,
                                               const float* __restrict__ g,
                                               const float* __restrict__ b,
                                               short* __restrict__ out) {
  const int row = blockIdx.x;
  const int t = threadIdx.x;
  const float* xr = x + (size_t)row * D_MODEL;
  float4 v = *(const float4*)(xr + t * 4);
  float s = v.x + v.y + v.z + v.w;
  float s2 = v.x * v.x + v.y * v.y + v.z * v.z + v.w * v.w;
#pragma unroll
  for (int m = 1; m < 64; m <<= 1) { s += __shfl_xor(s, m); s2 += __shfl_xor(s2, m); }
  __shared__ float ps[8];
  const int wid = t >> 6, lane = t & 63;
  if (lane == 0) { ps[wid] = s; ps[wid + 4] = s2; }
  __syncthreads();
  s = ps[0] + ps[1] + ps[2] + ps[3];
  s2 = ps[4] + ps[5] + ps[6] + ps[7];
  float mu = s * (1.f / D_MODEL);
  float rstd = rsqrtf(s2 * (1.f / D_MODEL) - mu * mu + 1e-5f);
  float4 gv = *(const float4*)(g + t * 4);
  float4 bv = *(const float4*)(b + t * 4);
  short4 o;
  o.x = f2bf((v.x - mu) * rstd * gv.x + bv.x);
  o.y = f2bf((v.y - mu) * rstd * gv.y + bv.y);
  o.z = f2bf((v.z - mu) * rstd * gv.z + bv.z);
  o.w = f2bf((v.w - mu) * rstd * gv.w + bv.w);
  *(short4*)(out + (size_t)row * D_MODEL + t * 4) = o;
}

// ---------------- 8-phase BMx256 bf16 MFMA GEMM, BK=64 (2 K-halves), counted vmcnt
// 512 threads = 8 waves (2M x 4N).
// MODE 0: QKV scatter. q,k,v -> [BH][S][HD] (q scaled by 1/8*log2e)
// MODE 1/3: C + bias0 + resid -> outf (fp32)
// MODE 2: gelu(C + bias0) -> outb0 (bf16)
template <int BM, int MODE>
__global__ __launch_bounds__(512, 2) void gemm8p(const short* __restrict__ A,
                                                 const short* __restrict__ Bt,
                                                 const float* __restrict__ bias0,
                                                 const float* __restrict__ bias1,
                                                 const float* __restrict__ bias2,
                                                 const float* resid, float* outf,
                                                 short* outb0, short* outb1, short* outb2,
                                                 int M, int N, int K) {
  constexpr int FM = BM / 32;
  constexpr int HM = FM / 2;
  constexpr int GA = BM / 128;
  constexpr int ABUF = BM * 64;
  constexpr int BBUF = 256 * 64;
  constexpr int BUFS = ABUF + BBUF;
  __shared__ short lds[2 * BUFS];

  const int tid = threadIdx.x;
  const int lane = tid & 63;
  const int wid = tid >> 6;
  const int wr = wid >> 2, wc = wid & 3;
  const int l15 = lane & 15, l4 = lane >> 4;

  const int nwg = gridDim.x;
  const int id = blockIdx.x;
  const int swz = (id & 7) * (nwg >> 3) + (id >> 3);
  const int nbx = N >> 8;
  const int by = swz / nbx, bx = swz - by * nbx;
  const int row0 = by * BM, col0 = bx * 256;

  f32x4 acc[FM][4];
#pragma unroll
  for (int i = 0; i < FM; ++i)
#pragma unroll
    for (int j = 0; j < 4; ++j) acc[i][j] = (f32x4){0.f, 0.f, 0.f, 0.f};

  const int NT = K >> 6;

  auto STAGE = [&](int buf, int t, int kh) {
    const int k0 = t * 64 + kh * 32;
    short* ab = lds + buf * BUFS + kh * (BM * 32);
#pragma unroll
    for (int s = 0; s < GA; ++s) {
      const int r = s * 128 + (tid >> 2);
      const int g = (tid & 3) ^ ((r >> 1) & 3);
      gload16(A + (size_t)(row0 + r) * K + k0 + g * 8, ab + s * 4096 + tid * 8);
    }
    short* bb = lds + buf * BUFS + ABUF + kh * (256 * 32);
#pragma unroll
    for (int s = 0; s < 2; ++s) {
      const int r = s * 128 + (tid >> 2);
      const int g = (tid & 3) ^ ((r >> 1) & 3);
      gload16(Bt + (size_t)(col0 + r) * K + k0 + g * 8, bb + s * 4096 + tid * 8);
    }
  };

  auto LDA = [&](bf16x8* dst, int buf, int kh, int h) {
    const short* ab = lds + buf * BUFS + kh * (BM * 32);
#pragma unroll
    for (int i = 0; i < HM; ++i) {
      const int R = wr * (BM / 2) + (h * HM + i) * 16 + l15;
      dst[i] = *(const bf16x8*)(ab + R * 32 + ((l4 ^ ((R >> 1) & 3)) << 3));
    }
  };
  auto LDB = [&](bf16x8* dst, int buf, int kh) {
    const short* bb = lds + buf * BUFS + ABUF + kh * (256 * 32);
#pragma unroll
    for (int nf = 0; nf < 4; ++nf) {
      const int R = wc * 64 + nf * 16 + l15;
      dst[nf] = *(const bf16x8*)(bb + R * 32 + ((l4 ^ ((R >> 1) & 3)) << 3));
    }
  };

  bf16x8 Af[HM], Bf[4];

  STAGE(0, 0, 0);
  STAGE(0, 0, 1);
  if (GA == 1) { VMC(3); } else { VMC(4); }
  BARRIER();

  for (int t = 0; t < NT; ++t) {
    const int b = t & 1;
    const bool nst = (t + 1 < NT);

#pragma unroll
    for (int kh = 0; kh < 2; ++kh) {
      LDA(Af, b, kh, 0);
      LDB(Bf, b, kh);
      if (nst) STAGE(b ^ 1, t + 1, kh);
      BARRIER();
      LGKM0();
      __builtin_amdgcn_s_setprio(1);
#pragma unroll
      for (int i = 0; i < HM; ++i)
#pragma unroll
        for (int nf = 0; nf < 4; ++nf)
          acc[i][nf] = __builtin_amdgcn_mfma_f32_16x16x32_bf16(Af[i], Bf[nf], acc[i][nf], 0, 0, 0);
      __builtin_amdgcn_s_setprio(0);
      BARRIER();

      LDA(Af, b, kh, 1);
      BARRIER();
      LGKM0();
      __builtin_amdgcn_s_setprio(1);
#pragma unroll
      for (int i = 0; i < HM; ++i)
#pragma unroll
        for (int nf = 0; nf < 4; ++nf)
          acc[HM + i][nf] =
              __builtin_amdgcn_mfma_f32_16x16x32_bf16(Af[i], Bf[nf], acc[HM + i][nf], 0, 0, 0);
      __builtin_amdgcn_s_setprio(0);
      if (kh == 0) {
        if (nst) {
          if (GA == 1) { VMC(3); } else { VMC(4); }
        } else {
          VMC(0);
        }
      } else {
        if (GA == 1) { VMC(3); } else { VMC(4); }
      }
      BARRIER();
    }
  }

  // epilogue
#pragma unroll
  for (int mf = 0; mf < FM; ++mf) {
#pragma unroll
    for (int nf = 0; nf < 4; ++nf) {
      const int rowb = row0 + wr * (BM / 2) + mf * 16 + (l4 << 2);
      const int col = col0 + wc * 64 + nf * 16 + l15;
      if (MODE == 0) {
        const int which = col >> 10, nn = col & 1023;
        const int hh = nn >> 6, dd = nn & 63;
        const float bias = (which == 0 ? bias0[nn] : which == 1 ? bias1[nn] : bias2[nn]);
        short* o = (which == 0 ? outb0 : which == 1 ? outb1 : outb2);
#pragma unroll
        for (int r = 0; r < 4; ++r) {
          const int row = rowb + r;
          float val = acc[mf][nf][r] + bias;
          if (which == 0) val *= 0.18033688011112042f;  // 1/8 * log2(e)
          const int bb = row >> 11, s = row & 2047;
          const size_t dst = (((size_t)((bb << 4) + hh) << 11) + s) * HD + dd;
          o[dst] = f2bf(val);
        }
      } else {
#pragma unroll
        for (int r = 0; r < 4; ++r) {
          const int row = rowb + r;
          float val = acc[mf][nf][r];
          if (MODE == 2) {
            val += bias0[col];
            float gl = 0.5f * val * (1.f + erff(val * 0.70710678118f));
            outb0[(size_t)row * N + col] = f2bf(gl);
          } else {
            val += bias0[col] + resid[(size_t)row * N + col];
            outf[(size_t)row * N + col] = val;
          }
        }
      }
    }
  }
}

// ---------------- flash attention, swapped-QK^T in-register softmax
// + raw v_exp + ones-MFMA row-sum (denominator on the MFMA pipe)
__global__ __launch_bounds__(256) void attn_swp(const short* __restrict__ q,
                                                const short* __restrict__ k,
                                                const short* __restrict__ vT,
                                                short* __restrict__ ctx) {
  __shared__ short Ks[2][4096];
  __shared__ short VTs[2][4096];
  const int tid = threadIdx.x;
  const int lane = tid & 63;
  const int wid = tid >> 6;
  const int hi = lane >> 5, l31 = lane & 31, l7 = lane & 7;
  const int qt = blockIdx.x, bh = blockIdx.y;
  const size_t base = (size_t)bh * SEQ * HD;
  const int q0 = qt * 128 + wid * 32;

  bf16x8 qf[4];
#pragma unroll
  for (int ks = 0; ks < 4; ++ks)
    qf[ks] = *(const bf16x8*)(q + base + (size_t)(q0 + l31) * HD + ks * 16 + hi * 8);

  bf16x8 onesv;
#pragma unroll
  for (int i = 0; i < 8; ++i) onesv[i] = (short)0x3F80;  // bf16 1.0

  f32x16 o0, o1, o2;
#pragma unroll
  for (int r = 0; r < 16; ++r) { o0[r] = 0.f; o1[r] = 0.f; o2[r] = 0.f; }
  float mreg = -1e30f;

  const int sch = (tid & 7) ^ ((tid >> 3) & 7);

#define STAGE_AT(bi, kt)                                                            \
  {                                                                                 \
    const short* kb_ = k + base + (size_t)(kt) * 64 * HD;                           \
    const short* vb_ = vT + base + (size_t)(kt) * 64;                               \
    _Pragma("unroll") for (int p = 0; p < 2; ++p)                                   \
        gload16(kb_ + (size_t)(p * 32 + (tid >> 3)) * HD + sch * 8,                 \
                Ks[bi] + p * 2048 + tid * 8);                                       \
    _Pragma("unroll") for (int p = 0; p < 2; ++p)                                   \
        gload16(vb_ + (size_t)(p * 32 + (tid >> 3)) * SEQ + sch * 8,                \
                VTs[bi] + p * 2048 + tid * 8);                                      \
  }

  STAGE_AT(0, 0);
  __syncthreads();
  int cur = 0;

  for (int kt = 0; kt < SEQ / 64; ++kt) {
    if (kt + 1 < SEQ / 64) STAGE_AT(cur ^ 1, kt + 1);

    // S^T = K . Q^T
    f32x16 s0, s1;
#pragma unroll
    for (int r = 0; r < 16; ++r) { s0[r] = 0.f; s1[r] = 0.f; }
#pragma unroll
    for (int ks = 0; ks < 4; ++ks) {
      const int ch = ((ks * 2 + hi) ^ l7) << 3;
      bf16x8 ka0 = *(const bf16x8*)(Ks[cur] + l31 * 64 + ch);
      bf16x8 ka1 = *(const bf16x8*)(Ks[cur] + (32 + l31) * 64 + ch);
      s0 = __builtin_amdgcn_mfma_f32_32x32x16_bf16(ka0, qf[ks], s0, 0, 0, 0);
      s1 = __builtin_amdgcn_mfma_f32_32x32x16_bf16(ka1, qf[ks], s1, 0, 0, 0);
    }

    // row max via v_max3 tree (32 values)
    float pm;
    {
      float t0 = fmax3(s0[0], s0[1], s0[2]);
      float t1 = fmax3(s0[3], s0[4], s0[5]);
      float t2 = fmax3(s0[6], s0[7], s0[8]);
      float t3 = fmax3(s0[9], s0[10], s0[11]);
      float t4 = fmax3(s0[12], s0[13], s0[14]);
      float t5 = fmax3(s0[15], s1[0], s1[1]);
      float t6 = fmax3(s1[2], s1[3], s1[4]);
      float t7 = fmax3(s1[5], s1[6], s1[7]);
      float t8 = fmax3(s1[8], s1[9], s1[10]);
      float t9 = fmax3(s1[11], s1[12], s1[13]);
      float ta = fmaxf(s1[14], s1[15]);
      float u0 = fmax3(t0, t1, t2);
      float u1 = fmax3(t3, t4, t5);
      float u2 = fmax3(t6, t7, t8);
      float u3 = fmaxf(t9, ta);
      pm = fmax3(fmaxf(u0, u1), u2, u3);
    }
    {
      int2v mm = __builtin_amdgcn_permlane32_swap(__builtin_bit_cast(int, pm),
                                                  __builtin_bit_cast(int, pm), false, false);
      pm = fmaxf(__builtin_bit_cast(float, mm[0]), __builtin_bit_cast(float, mm[1]));
    }
    // defer-max: rescale only when max grew by > 8 (log2 domain)
    if (!__all(pm <= mreg + 8.f)) {
      float mn = fmaxf(mreg, pm);
      float al = fexp2(mreg - mn);
      mreg = mn;
#pragma unroll
      for (int r = 0; r < 16; ++r) { o0[r] *= al; o1[r] *= al; o2[r] *= al; }
    }

    // P = exp2(S - m)  (raw v_exp)
#pragma unroll
    for (int r = 0; r < 16; ++r) s0[r] = fexp2(s0[r] - mreg);
#pragma unroll
    for (int r = 0; r < 16; ++r) s1[r] = fexp2(s1[r] - mreg);

    // pack P -> PV B-operand fragments
    uint4v pw[4];
#pragma unroll
    for (int t = 0; t < 2; ++t) {
#pragma unroll
      for (int ks = 0; ks < 2; ++ks) {
        const f32x16& st = t ? s1 : s0;
        unsigned x0 = cvt_pk_bf16(st[8 * ks + 0], st[8 * ks + 1]);
        unsigned x1 = cvt_pk_bf16(st[8 * ks + 2], st[8 * ks + 3]);
        unsigned y0 = cvt_pk_bf16(st[8 * ks + 4], st[8 * ks + 5]);
        unsigned y1 = cvt_pk_bf16(st[8 * ks + 6], st[8 * ks + 7]);
        int2v a0 = __builtin_amdgcn_permlane32_swap((int)y0, (int)x0, false, false);
        int2v a1 = __builtin_amdgcn_permlane32_swap((int)y1, (int)x1, false, false);
        pw[t * 2 + ks] = (uint4v){(unsigned)a0[1], (unsigned)a1[1],
                                  (unsigned)a0[0], (unsigned)a1[0]};
      }
    }

    // O^T += V^T . P^T ; o2 += ones . P^T (row-sum on MFMA pipe)
#pragma unroll
    for (int s = 0; s < 4; ++s) {
      bf16x8 pf = __builtin_bit_cast(bf16x8, pw[s]);
      const int ch = ((s * 2 + hi) ^ l7) << 3;
      bf16x8 v0 = *(const bf16x8*)(VTs[cur] + l31 * 64 + ch);
      bf16x8 v1 = *(const bf16x8*)(VTs[cur] + (32 + l31) * 64 + ch);
      o0 = __builtin_amdgcn_mfma_f32_32x32x16_bf16(v0, pf, o0, 0, 0, 0);
      o1 = __builtin_amdgcn_mfma_f32_32x32x16_bf16(v1, pf, o1, 0, 0, 0);
      o2 = __builtin_amdgcn_mfma_f32_32x32x16_bf16(onesv, pf, o2, 0, 0, 0);
    }
    __syncthreads();
    cur ^= 1;
  }
#undef STAGE_AT

  // epilogue
  const int b = bh >> 4, hh = bh & 15;
  const float inv = 1.f / o2[0];
  const size_t tokoff = ((size_t)(b * SEQ + q0 + l31)) * D_MODEL + hh * HD;
#pragma unroll
  for (int r = 0; r < 16; ++r) {
    const int d = (r & 3) + 8 * (r >> 2) + 4 * hi;
    ctx[tokoff + d] = f2bf(o0[r] * inv);
    ctx[tokoff + 32 + d] = f2bf(o1[r] * inv);
  }
}

// ---------------- launcher
extern "C" void kernel_launch(void* const* d_in, const int* in_sizes, int n_in,
                              void* d_out, int out_size, void* d_ws, size_t ws_size,
                              hipStream_t stream) {
  const float* x  = (const float*)d_in[0];
  const float* Wq = (const float*)d_in[1];
  const float* bq = (const float*)d_in[2];
  const float* Wk = (const float*)d_in[3];
  const float* bk = (const float*)d_in[4];
  const float* Wv = (const float*)d_in[5];
  const float* bv = (const float*)d_in[6];
  const float* Wo = (const float*)d_in[7];
  const float* bo = (const float*)d_in[8];
  const float* g1 = (const float*)d_in[9];
  const float* b1 = (const float*)d_in[10];
  const float* g2 = (const float*)d_in[11];
  const float* b2 = (const float*)d_in[12];
  const float* W1 = (const float*)d_in[13];
  const float* bf1 = (const float*)d_in[14];
  const float* W2 = (const float*)d_in[15];
  const float* bf2 = (const float*)d_in[16];

  char* w = (char*)d_ws;
  short* WqkvT = (short*)w; w += (size_t)3072 * 1024 * 2;      // 6 MB
  short* WoT   = (short*)w; w += (size_t)1024 * 1024 * 2;      // 2 MB
  short* W1T   = (short*)w; w += (size_t)2048 * 1024 * 2;      // 4 MB
  short* W2T   = (short*)w; w += (size_t)1024 * 2048 * 2;      // 4 MB
  short* xn    = (short*)w; w += (size_t)M_TOK * 1024 * 2;     // 16 MB
  short* qb    = (short*)w; w += (size_t)M_TOK * 1024 * 2;
  short* kb    = (short*)w; w += (size_t)M_TOK * 1024 * 2;
  short* vTb   = (short*)w; w += (size_t)M_TOK * 1024 * 2;     // [BH][HD][SEQ]
  short* ctxb  = (short*)w; w += (size_t)M_TOK * 1024 * 2;
  short* xn2   = (short*)w; w += (size_t)M_TOK * 1024 * 2;
  short* hb    = (short*)w; w += (size_t)M_TOK * 2048 * 2;     // 32 MB
  short* vb    = hb;  // V row-major temp; lifetime disjoint from FFN hidden

  dim3 blk(256);

  // all weight transposes in one launch
  transpose_all<<<dim3(2048), blk, 0, stream>>>(Wq, Wk, Wv, Wo, W1, W2,
                                                WqkvT, WoT, W1T, W2T);

  // LN1
  ln_bf16<<<M_TOK, blk, 0, stream>>>(x, g1, b1, xn);

  // QKV projection (all outputs coalesced row-major [BH][S][HD])
  gemm8p<256, 0><<<dim3(12 * 32), dim3(512), 0, stream>>>(
      xn, WqkvT, bq, bk, bv, nullptr, nullptr, qb, kb, vb, M_TOK, 3072, 1024);

  // V -> V^T (coalesced LDS-tiled transpose)
  transpose_v<<<dim3(SEQ / 64, BATCH * H_NUM), blk, 0, stream>>>(vb, vTb);

  // attention
  attn_swp<<<dim3(16, 64), blk, 0, stream>>>(qb, kb, vTb, ctxb);

  // out proj + residual -> d_out (fp32 x2)
  gemm8p<128, 1><<<dim3(4 * 64), dim3(512), 0, stream>>>(
      ctxb, WoT, bo, nullptr, nullptr, x, (float*)d_out, nullptr, nullptr, nullptr,
      M_TOK, 1024, 1024);

  // LN2
  ln_bf16<<<M_TOK, blk, 0, stream>>>((const float*)d_out, g2, b2, xn2);

  // FFN1 + GELU
  gemm8p<256, 2><<<dim3(8 * 32), dim3(512), 0, stream>>>(
      xn2, W1T, bf1, nullptr, nullptr, nullptr, nullptr, hb, nullptr, nullptr,
      M_TOK, 2048, 1024);

  // FFN2 + residual (in-place on d_out)
  gemm8p<128, 3><<<dim3(4 * 64), dim3(512), 0, stream>>>(
      hb, W2T, bf2, nullptr, nullptr, (const float*)d_out, (float*)d_out,
      nullptr, nullptr, nullptr, M_TOK, 1024, 2048);
}